// Round 2
// baseline (160.174 us; speedup 1.0000x reference)
//
#include <hip/hip_runtime.h>
#include <math.h>

#define N 16384
#define MD 512
#define CTRLDIM 1024
#define OUTF 1542  // 3*512+6

// ws layout (floats):
//   [0    .. 1541]   O    projection output o
//   [2048 .. 2055]   SC   scalars: beta, g, s0, s1, s2, gamma, k_norm
//   [2112 .. 2623]   E    erase vec (16B-aligned)
//   [2688 .. 3199]   A    add vec (16B-aligned)
//   [3200]           SUM1 sum of exp (softmax denom)
//   [3204]           SUM2 sum of wp (sharpen denom)   <- float index 3201? no: use 3201
//   [4096 .. 20479]  EZ   exp(beta*sim - beta) per row
//   [20480.. 36863]  WP   (ws+eps)^gamma per row

__device__ __forceinline__ float softplus_f(float x) {
    return (x > 20.f) ? x : log1pf(expf(x));
}

// o[row] = dot(W[row,:], emb) + b[row]   (one block per row, 256 thr x 4 elem)
__global__ void k_proj(const float* __restrict__ emb, const float* __restrict__ W,
                       const float* __restrict__ b, float* __restrict__ O) {
    int row = blockIdx.x;
    int t = threadIdx.x;
    const float4* w4 = (const float4*)(W + (size_t)row * CTRLDIM);
    const float4* e4 = (const float4*)emb;
    float4 wv = w4[t];
    float4 ev = e4[t];
    float p = wv.x * ev.x + wv.y * ev.y + wv.z * ev.z + wv.w * ev.w;
    #pragma unroll
    for (int off = 32; off; off >>= 1) p += __shfl_down(p, off, 64);
    __shared__ float s[4];
    int lane = t & 63, wid = t >> 6;
    if (lane == 0) s[wid] = p;
    __syncthreads();
    if (t == 0) O[row] = s[0] + s[1] + s[2] + s[3] + b[row];
}

// scalars (k_norm, beta, g, softmax s, gamma) + aligned copies of e, a + zero accumulators
__global__ void k_scal(const float* __restrict__ O, float* __restrict__ SC,
                       float* __restrict__ E, float* __restrict__ A,
                       float* __restrict__ SUMS) {
    int t = threadIdx.x;  // 512
    float kv = O[t];
    float sq = kv * kv;
    #pragma unroll
    for (int off = 32; off; off >>= 1) sq += __shfl_down(sq, off, 64);
    __shared__ float s[8];
    int lane = t & 63, wid = t >> 6;
    if (lane == 0) s[wid] = sq;
    E[t] = O[MD + 6 + t];
    A[t] = O[2 * MD + 6 + t];
    __syncthreads();
    if (t == 0) {
        float ksq = 0.f;
        #pragma unroll
        for (int i = 0; i < 8; i++) ksq += s[i];
        float knorm = sqrtf(ksq);
        float beta = softplus_f(O[MD]);
        float g = 1.f / (1.f + expf(-O[MD + 1]));
        float s0 = O[MD + 2], s1 = O[MD + 3], s2 = O[MD + 4];
        float m = fmaxf(s0, fmaxf(s1, s2));
        float e0 = expf(s0 - m), e1 = expf(s1 - m), e2 = expf(s2 - m);
        float se = e0 + e1 + e2;
        float gamma = 1.f + softplus_f(O[MD + 5]);
        SC[0] = beta; SC[1] = g; SC[2] = e0 / se; SC[3] = e1 / se; SC[4] = e2 / se;
        SC[5] = gamma; SC[6] = knorm;
        SUMS[0] = 0.f;  // SUM1
        SUMS[1] = 0.f;  // SUM2
    }
}

// EZ[row] = exp(beta*sim - beta), sim = dot(k,mem[row]) / (|k||mem[row]| + EPS)
// (wave per row; block partial-sum -> one atomicAdd into SUM1)
__global__ void k_sim(const float* __restrict__ mem, const float* __restrict__ O,
                      const float* __restrict__ SC, float* __restrict__ EZ,
                      float* __restrict__ SUMS) {
    int wid = threadIdx.x >> 6;
    int lane = threadIdx.x & 63;
    int row = blockIdx.x * 4 + wid;
    const float4* m4 = (const float4*)(mem + (size_t)row * MD);
    const float4* k4 = (const float4*)O;
    float dot = 0.f, nsq = 0.f;
    #pragma unroll
    for (int c = 0; c < 2; c++) {
        int j = lane + c * 64;
        float4 m = m4[j];
        float4 k = k4[j];
        dot += m.x * k.x + m.y * k.y + m.z * k.z + m.w * k.w;
        nsq += m.x * m.x + m.y * m.y + m.z * m.z + m.w * m.w;
    }
    #pragma unroll
    for (int off = 32; off; off >>= 1) {
        dot += __shfl_down(dot, off, 64);
        nsq += __shfl_down(nsq, off, 64);
    }
    __shared__ float sblk[4];
    if (lane == 0) {
        float beta = SC[0], knorm = SC[6];
        float z = beta * dot / (knorm * sqrtf(nsq) + 1e-16f);
        float ez = expf(z - beta);   // z <= beta, so exponent <= 0: safe, max cancels in softmax
        EZ[row] = ez;
        sblk[wid] = ez;
    }
    __syncthreads();
    if (threadIdx.x == 0)
        atomicAdd(&SUMS[0], sblk[0] + sblk[1] + sblk[2] + sblk[3]);
}

// grid-wide: wc=EZ/SUM1 -> wg -> circular 3-tap shift -> wp=(ws+eps)^gamma -> SUM2
__global__ void k_shift(const float* __restrict__ EZ, const float* __restrict__ wprev,
                        const float* __restrict__ SC, const float* __restrict__ SUMS,
                        float* __restrict__ WP, float* __restrict__ SUMS_out) {
    int i = blockIdx.x * 256 + threadIdx.x;
    float inv1 = 1.f / SUMS[0];
    float g = SC[1], s0 = SC[2], s1 = SC[3], s2 = SC[4], gamma = SC[5];
    float gm1 = 1.f - g;
    int im = (i == 0) ? (N - 1) : (i - 1);
    int ip = (i == N - 1) ? 0 : (i + 1);
    float wgm = g * EZ[im] * inv1 + gm1 * wprev[im];
    float wgc = g * EZ[i]  * inv1 + gm1 * wprev[i];
    float wgp = g * EZ[ip] * inv1 + gm1 * wprev[ip];
    float wsv = s0 * wgm + s1 * wgc + s2 * wgp;
    // ws >= 0 always (all terms nonneg) -> pow via hw log2/exp2
    float wp = exp2f(gamma * log2f(wsv + 1e-16f));
    WP[i] = wp;
    // block reduce -> one atomic
    #pragma unroll
    for (int off = 32; off; off >>= 1) wp += __shfl_down(wp, off, 64);
    __shared__ float s[4];
    int lane = threadIdx.x & 63, wid = threadIdx.x >> 6;
    if (lane == 0) s[wid] = wp;
    __syncthreads();
    if (threadIdx.x == 0)
        atomicAdd(&SUMS_out[1], s[0] + s[1] + s[2] + s[3]);
}

// w = WP/SUM2 (write to out) ; new_memory = memory * (1 - w_i*e_j) + w_i*a_j
__global__ void k_upd(const float* __restrict__ mem, const float* __restrict__ WP,
                      const float* __restrict__ SUMS,
                      const float* __restrict__ E, const float* __restrict__ A,
                      float* __restrict__ wout, float* __restrict__ outMem) {
    int idx = blockIdx.x * blockDim.x + threadIdx.x;  // 0 .. N*128-1 (float4 units)
    int i = idx >> 7;
    int c = idx & 127;
    float inv2 = 1.f / SUMS[1];
    float wi = WP[i] * inv2;
    if (c == 0) wout[i] = wi;
    float4 m = ((const float4*)mem)[idx];
    float4 e = ((const float4*)E)[c];
    float4 a = ((const float4*)A)[c];
    float4 o;
    o.x = m.x * (1.f - wi * e.x) + wi * a.x;
    o.y = m.y * (1.f - wi * e.y) + wi * a.y;
    o.z = m.z * (1.f - wi * e.z) + wi * a.z;
    o.w = m.w * (1.f - wi * e.w) + wi * a.w;
    ((float4*)outMem)[idx] = o;
}

extern "C" void kernel_launch(void* const* d_in, const int* in_sizes, int n_in,
                              void* d_out, int out_size, void* d_ws, size_t ws_size,
                              hipStream_t stream) {
    const float* emb   = (const float*)d_in[0];
    const float* wprev = (const float*)d_in[1];
    const float* mem   = (const float*)d_in[2];
    const float* W     = (const float*)d_in[3];
    const float* b     = (const float*)d_in[4];
    float* out = (float*)d_out;
    float* wsf = (float*)d_ws;
    float* O    = wsf;
    float* SC   = wsf + 2048;
    float* E    = wsf + 2112;
    float* A    = wsf + 2688;
    float* SUMS = wsf + 3200;
    float* EZ   = wsf + 4096;
    float* WP   = wsf + 20480;

    k_proj<<<OUTF, 256, 0, stream>>>(emb, W, b, O);
    k_scal<<<1, 512, 0, stream>>>(O, SC, E, A, SUMS);
    k_sim<<<N / 4, 256, 0, stream>>>(mem, O, SC, EZ, SUMS);
    k_shift<<<N / 256, 256, 0, stream>>>(EZ, wprev, SC, SUMS, WP, SUMS);
    k_upd<<<(N * (MD / 4)) / 256, 256, 0, stream>>>(mem, WP, SUMS, E, A, out, out + N);
}

// Round 3
// 110.944 us; speedup vs baseline: 1.4437x; 1.4437x over previous
//
#include <hip/hip_runtime.h>
#include <math.h>

#define N 16384
#define MD 512
#define CTRLDIM 1024
#define OUTF 1542  // 3*512+6

// ws layout (floats):
//   [0    .. 1541]   O      projection output o
//   [1552 .. 2063]   E      erase vec (16B-aligned)
//   [2064 .. 2575]   A      add vec (16B-aligned)
//   [2576 .. 3599]   PART1  per-block partial sums of exp (k_sim, 1024 blocks)
//   [3600 .. 3663]   PART2  per-block partial sums of wp (k_shift, 64 blocks)
//   [3664 .. 20047]  EZ     exp(beta*sim - beta) per row
//   [20048.. 36431]  WP     (ws+eps)^gamma per row
// No atomics anywhere: partials written to private slots; consumers reduce
// redundantly per-wave (butterfly shuffle -> every lane has the total).

__device__ __forceinline__ float softplus_f(float x) {
    return (x > 20.f) ? x : log1pf(expf(x));
}

__device__ __forceinline__ float wave_bfly_sum(float v) {
    #pragma unroll
    for (int off = 1; off < 64; off <<= 1) v += __shfl_xor(v, off, 64);
    return v;
}

// o[row] = dot(W[row,:], emb) + b[row]; rows >= 518 also scatter into aligned E/A
__global__ void k_proj(const float* __restrict__ emb, const float* __restrict__ W,
                       const float* __restrict__ b, float* __restrict__ O,
                       float* __restrict__ E, float* __restrict__ A) {
    int row = blockIdx.x;
    int t = threadIdx.x;
    const float4* w4 = (const float4*)(W + (size_t)row * CTRLDIM);
    const float4* e4 = (const float4*)emb;
    float4 wv = w4[t];
    float4 ev = e4[t];
    float p = wv.x * ev.x + wv.y * ev.y + wv.z * ev.z + wv.w * ev.w;
    #pragma unroll
    for (int off = 32; off; off >>= 1) p += __shfl_down(p, off, 64);
    __shared__ float s[4];
    int lane = t & 63, wid = t >> 6;
    if (lane == 0) s[wid] = p;
    __syncthreads();
    if (t == 0) {
        float val = s[0] + s[1] + s[2] + s[3] + b[row];
        O[row] = val;
        if (row >= MD + 6 && row < 2 * MD + 6)      E[row - (MD + 6)] = val;
        else if (row >= 2 * MD + 6)                 A[row - (2 * MD + 6)] = val;
    }
}

// wave per 4 rows: EZ[row] = exp(beta*sim - beta); block partial -> PART1[blk]
// (sim <= 1 so exponent <= 0: the softmax max-shift by beta is exact & free)
__global__ void __launch_bounds__(256) k_sim(const float* __restrict__ mem,
                                             const float* __restrict__ O,
                                             float* __restrict__ EZ,
                                             float* __restrict__ PART1) {
    int t = threadIdx.x, lane = t & 63, wid = t >> 6;
    int waveId = blockIdx.x * 4 + wid;  // 0..4095
    const float4* k4 = (const float4*)O;
    float4 k0 = k4[lane], k1 = k4[lane + 64];
    float ksq = k0.x * k0.x + k0.y * k0.y + k0.z * k0.z + k0.w * k0.w
              + k1.x * k1.x + k1.y * k1.y + k1.z * k1.z + k1.w * k1.w;
    ksq = wave_bfly_sum(ksq);
    float knorm = sqrtf(ksq);
    float beta = softplus_f(O[MD]);
    int row0 = waveId * 4;
    float4 m0[4], m1[4];
    #pragma unroll
    for (int r = 0; r < 4; r++) {
        const float4* m4 = (const float4*)(mem + (size_t)(row0 + r) * MD);
        m0[r] = m4[lane];
        m1[r] = m4[lane + 64];
    }
    float wsum = 0.f;
    #pragma unroll
    for (int r = 0; r < 4; r++) {
        float dot = m0[r].x * k0.x + m0[r].y * k0.y + m0[r].z * k0.z + m0[r].w * k0.w
                  + m1[r].x * k1.x + m1[r].y * k1.y + m1[r].z * k1.z + m1[r].w * k1.w;
        float nsq = m0[r].x * m0[r].x + m0[r].y * m0[r].y + m0[r].z * m0[r].z + m0[r].w * m0[r].w
                  + m1[r].x * m1[r].x + m1[r].y * m1[r].y + m1[r].z * m1[r].z + m1[r].w * m1[r].w;
        dot = wave_bfly_sum(dot);
        nsq = wave_bfly_sum(nsq);
        float z = beta * dot / (knorm * sqrtf(nsq) + 1e-16f);
        float ez = expf(z - beta);
        if (lane == 0) EZ[row0 + r] = ez;
        wsum += ez;  // identical in all lanes
    }
    __shared__ float sblk[4];
    if (lane == 0) sblk[wid] = wsum;
    __syncthreads();
    if (t == 0) PART1[blockIdx.x] = sblk[0] + sblk[1] + sblk[2] + sblk[3];
}

// grid-wide: SUM1 from PART1 (per-wave redundant reduce) -> wc -> wg ->
// circular 3-tap shift -> wp=(ws+eps)^gamma -> PART2[blk]
__global__ void __launch_bounds__(256) k_shift(const float* __restrict__ EZ,
                                               const float* __restrict__ wprev,
                                               const float* __restrict__ O,
                                               const float* __restrict__ PART1,
                                               float* __restrict__ WP,
                                               float* __restrict__ PART2) {
    int t = threadIdx.x, lane = t & 63, wid = t >> 6;
    float v = 0.f;
    #pragma unroll
    for (int j = 0; j < 16; j++) v += PART1[lane + j * 64];
    float inv1 = 1.f / wave_bfly_sum(v);
    // uniform scalars, recomputed per thread (cheap)
    float g = 1.f / (1.f + expf(-O[MD + 1]));
    float s0r = O[MD + 2], s1r = O[MD + 3], s2r = O[MD + 4];
    float m = fmaxf(s0r, fmaxf(s1r, s2r));
    float e0 = expf(s0r - m), e1 = expf(s1r - m), e2 = expf(s2r - m);
    float inv_se = 1.f / (e0 + e1 + e2);
    float s0 = e0 * inv_se, s1 = e1 * inv_se, s2 = e2 * inv_se;
    float gamma = 1.f + softplus_f(O[MD + 5]);
    float gm1 = 1.f - g;
    int i = blockIdx.x * 256 + t;
    int im = (i == 0) ? (N - 1) : (i - 1);
    int ip = (i == N - 1) ? 0 : (i + 1);
    float wgm = g * EZ[im] * inv1 + gm1 * wprev[im];
    float wgc = g * EZ[i]  * inv1 + gm1 * wprev[i];
    float wgp = g * EZ[ip] * inv1 + gm1 * wprev[ip];
    float wsv = s0 * wgm + s1 * wgc + s2 * wgp;
    float wp = exp2f(gamma * log2f(wsv + 1e-16f));  // ws >= 0 always
    WP[i] = wp;
    float bs = wave_bfly_sum(wp);
    __shared__ float sblk[4];
    if (lane == 0) sblk[wid] = bs;
    __syncthreads();
    if (t == 0) PART2[blockIdx.x] = sblk[0] + sblk[1] + sblk[2] + sblk[3];
}

// SUM2 from PART2 (per-wave reduce); w = WP/SUM2 -> out;
// new_memory = memory * (1 - w_i*e_j) + w_i*a_j
__global__ void __launch_bounds__(256) k_upd(const float* __restrict__ mem,
                                             const float* __restrict__ WP,
                                             const float* __restrict__ PART2,
                                             const float* __restrict__ E,
                                             const float* __restrict__ A,
                                             float* __restrict__ wout,
                                             float* __restrict__ outMem) {
    int t = threadIdx.x, lane = t & 63;
    float inv2 = 1.f / wave_bfly_sum(PART2[lane]);  // exactly 64 entries
    int idx = blockIdx.x * 256 + t;                 // float4 units
    int i = idx >> 7;
    int c = idx & 127;
    float wi = WP[i] * inv2;
    if (c == 0) wout[i] = wi;
    float4 m = ((const float4*)mem)[idx];
    float4 e = ((const float4*)E)[c];
    float4 a = ((const float4*)A)[c];
    float4 o;
    o.x = m.x * (1.f - wi * e.x) + wi * a.x;
    o.y = m.y * (1.f - wi * e.y) + wi * a.y;
    o.z = m.z * (1.f - wi * e.z) + wi * a.z;
    o.w = m.w * (1.f - wi * e.w) + wi * a.w;
    ((float4*)outMem)[idx] = o;
}

extern "C" void kernel_launch(void* const* d_in, const int* in_sizes, int n_in,
                              void* d_out, int out_size, void* d_ws, size_t ws_size,
                              hipStream_t stream) {
    const float* emb   = (const float*)d_in[0];
    const float* wprev = (const float*)d_in[1];
    const float* mem   = (const float*)d_in[2];
    const float* W     = (const float*)d_in[3];
    const float* b     = (const float*)d_in[4];
    float* out = (float*)d_out;
    float* wsf = (float*)d_ws;
    float* O     = wsf;
    float* E     = wsf + 1552;
    float* A     = wsf + 2064;
    float* PART1 = wsf + 2576;
    float* PART2 = wsf + 3600;
    float* EZ    = wsf + 3664;
    float* WP    = wsf + 20048;

    k_proj<<<OUTF, 256, 0, stream>>>(emb, W, b, O, E, A);
    k_sim<<<N / 16, 256, 0, stream>>>(mem, O, EZ, PART1);           // 1024 blocks
    k_shift<<<N / 256, 256, 0, stream>>>(EZ, wprev, O, PART1, WP, PART2);  // 64 blocks
    k_upd<<<(N * (MD / 4)) / 256, 256, 0, stream>>>(mem, WP, PART2, E, A, out, out + N);
}